// Round 11
// baseline (113.164 us; speedup 1.0000x reference)
//
#include <hip/hip_runtime.h>
#include <hip/hip_bf16.h>
#include <math.h>

// SpectralLinear: out = x @ (M_U * diag(sigma) * M_V) + bias
// Compact WY without explicit T:  T^{-1} = strict_upper(G) + diag(1/beta)
//   A = Umat*T_U (forward subst)   R = T_V*Vmat^T (backward subst)
//   C = (Umat^T S) Vmat ;  E = SV - A*C ;  W = S - [A | E] . [SU^T ; R]
// Inputs U,V are already upper-triangular (setup applies jnp.triu).
// R5: no device-scope spin barriers. R7: no serial prologue in wide kernels.
// R9: 8-lane parallel recurrences fused into k_WtE (3 launches).
// R10: register-resident k_prep; BK=64 gemm.
// R11: wave-uniform triangle-skip in k_prep; nontemporal epilogue stores.

#define INSIZE 512
#define NREF 64
#define BATCH 8192

// workspace layout (float slots)
static constexpr int OFF_WT    = 0;                    // 512*512 bf16 = 131072 slots
static constexpr int OFF_SIGMA = 131072;               // 512
static constexpr int OFF_BETAU = OFF_SIGMA + 512;      // 64
static constexpr int OFF_BETAV = OFF_BETAU + 64;       // 64
static constexpr int OFF_GU    = OFF_BETAV + 64;       // 64*64 strict-UPPER masked
static constexpr int OFF_GV    = OFF_GU + 4096;        // 64*64 strict-LOWER masked
static constexpr int OFF_C     = OFF_GV + 4096;        // 64*64

__device__ inline float sigma_of(float pv) {
    float s = 1.0f / (1.0f + expf(-pv));
    return 0.55f + 0.9f * (s - 0.5f);   // SIGMA_MIN=0.1, SIGMA_MAX=1.0
}

__device__ inline float dot8(float4 a0, float4 a1, float4 b0, float4 b1) {
    return a0.x * b0.x + a0.y * b0.y + a0.z * b0.z + a0.w * b0.w
         + a1.x * b1.x + a1.y * b1.y + a1.z * b1.z + a1.w * b1.w;
}

// ---------------------------------------------------------------------------
// k_prep: blocks 0..63   -> G_U row i, j>=i only (beta from j==i)
//         blocks 64..127 -> G_V row i, j<=i only (packed: row 63-i)
//         blocks 128..191-> C row i
//         block 192      -> sigma
// Register-resident; triangle-skip branch is wave-uniform (i,j uniform).
__global__ __launch_bounds__(256) void k_prep(const float* __restrict__ U,
                                              const float* __restrict__ V,
                                              const float* __restrict__ p,
                                              float* __restrict__ ws) {
    int b = blockIdx.x, t = threadIdx.x;
    if (b == 192) {
        for (int c = t; c < INSIZE; c += 256)
            (ws + OFF_SIGMA)[c] = sigma_of(p[c]);
        return;
    }
    int w = t >> 6, l = t & 63;
    float4 b0, b1;
    if (b < 128) {
        bool isV = (b >= 64);
        int i = isV ? (b - 64) : b;
        const float* src = isV ? V : U;
        int srow = isV ? (63 - i) : i;
        const float4* ri4 = (const float4*)(src + srow * INSIZE);
        b0 = ri4[l * 2]; b1 = ri4[l * 2 + 1];
        float* G = ws + (isV ? OFF_GV : OFF_GU);
        float* beta = ws + (isV ? OFF_BETAV : OFF_BETAU);
        for (int jj = 0; jj < 16; ++jj) {
            int j = w * 16 + jj;
            bool keep = isV ? (j < i) : (j > i);   // masked triangle
            if (!keep && j != i) {                 // wave-uniform skip
                if (l == 0) G[i * 64 + j] = 0.0f;
                continue;
            }
            int jrow = isV ? (63 - j) : j;
            const float4* rj4 = (const float4*)(src + jrow * INSIZE);
            float s = dot8(rj4[l * 2], rj4[l * 2 + 1], b0, b1);
            for (int o = 32; o > 0; o >>= 1) s += __shfl_down(s, o, 64);
            if (l == 0) {
                G[i * 64 + j] = keep ? s : 0.0f;
                if (j == i) beta[i] = 2.0f / s;
            }
        }
    } else {
        int i = b - 128;
        const float4* ui4 = (const float4*)(U + i * INSIZE);
        const float4* p4 = (const float4*)p;
        float4 u0 = ui4[l * 2], u1 = ui4[l * 2 + 1];
        float4 p0 = p4[l * 2], p1 = p4[l * 2 + 1];
        b0.x = u0.x * sigma_of(p0.x); b0.y = u0.y * sigma_of(p0.y);
        b0.z = u0.z * sigma_of(p0.z); b0.w = u0.w * sigma_of(p0.w);
        b1.x = u1.x * sigma_of(p1.x); b1.y = u1.y * sigma_of(p1.y);
        b1.z = u1.z * sigma_of(p1.z); b1.w = u1.w * sigma_of(p1.w);
        float* C = ws + OFF_C;
        for (int jj = 0; jj < 16; ++jj) {
            int j = w * 16 + jj;
            const float4* rj4 = (const float4*)(V + (63 - j) * INSIZE);
            float s = dot8(rj4[l * 2], rj4[l * 2 + 1], b0, b1);
            for (int o = 32; o > 0; o >>= 1) s += __shfl_down(s, o, 64);
            if (l == 0) C[i * 64 + j] = s;
        }
    }
}

// ---------------------------------------------------------------------------
// Fused: parallel substitutions + E + W tile + transpose + bf16 cast.
// Validated R9/R10; unchanged.
__global__ __launch_bounds__(256) void k_WtE(const float* __restrict__ U,
                                             const float* __restrict__ V,
                                             float* __restrict__ ws) {
    __shared__ float Ps[128][34];
    __shared__ float Qs[128][34];
    __shared__ float Xs[4160];
    int t = threadIdx.x;
    int r0 = (blockIdx.x >> 4) * 32;
    int c0 = (blockIdx.x & 15) * 32;
    const float* sig = ws + OFF_SIGMA;
    float* Qf = &Qs[0][0];

    // ---- phase a: stage masked Gram matrices + betas
    for (int i = t; i < 1024; i += 256) {
        *(float4*)&Xs[i * 4] = *(const float4*)&(ws + OFF_GU)[i * 4];
        *(float4*)&Qf[i * 4] = *(const float4*)&(ws + OFF_GV)[i * 4];
    }
    if (t < 64) {
        Xs[4096 + t] = (ws + OFF_BETAU)[t];
        Qf[4096 + t] = (ws + OFF_BETAV)[t];
    }
    __syncthreads();

    // ---- phase b: 8-lane-per-column parallel recurrences
    int l = t & 63;
    int c_loc = (t >> 6) * 8 + (l >> 3);   // 0..31
    int grp = l & 7;
    int srcbase = l & 0x38;
    float pj[8], pr[8];
    {   // forward: At columns r0..r0+31
        int r = r0 + c_loc;
#pragma unroll
        for (int jj = 0; jj < 8; ++jj) pj[jj] = U[(grp * 8 + jj) * INSIZE + r];
#pragma unroll
        for (int m = 0; m < 64; ++m) {
            float tmp = pj[m & 7] * Xs[4096 + m];
            float am = __shfl(tmp, srcbase | (m >> 3), 64);
            if (grp == (m >> 3)) pj[m & 7] = am;
#pragma unroll
            for (int jj = 0; jj < 8; ++jj)
                pj[jj] -= am * Xs[m * 64 + grp * 8 + jj];   // masked: j<=m is 0
        }
#pragma unroll
        for (int jj = 0; jj < 8; ++jj) Ps[grp * 8 + jj][c_loc] = pj[jj];
    }
    {   // backward: R columns c0..c0+31 (G_V symmetric, strict-lower masked)
        int c = c0 + c_loc;
#pragma unroll
        for (int ii = 0; ii < 8; ++ii)
            pr[ii] = V[(63 - (grp * 8 + ii)) * INSIZE + c];
#pragma unroll
        for (int i = 63; i >= 0; --i) {
            float tmp = pr[i & 7] * Qf[4096 + i];
            float ai = __shfl(tmp, srcbase | (i >> 3), 64);
            if (grp == (i >> 3)) pr[i & 7] = ai;
#pragma unroll
            for (int ii = 0; ii < 8; ++ii)
                pr[ii] -= ai * Qf[i * 64 + grp * 8 + ii];   // masked: j>=i is 0
        }
    }
    __syncthreads();   // G_U/G_V dead; Ps rows 0..63 = At tile

    // ---- phase c: C -> Xs; Qs rows 0..63 = SU^T, rows 64..127 = R (regs)
    for (int i = t; i < 1024; i += 256)
        *(float4*)&Xs[i * 4] = *(const float4*)&(ws + OFF_C)[i * 4];
    int lr = t & 31, kb = t >> 5;         // kb 0..7
    float sc = sig[c0 + lr];
#pragma unroll
    for (int ii = 0; ii < 8; ++ii) {
        int k = kb + ii * 8;              // 0..63
        Qs[k][lr] = U[k * INSIZE + c0 + lr] * sc;
    }
#pragma unroll
    for (int ii = 0; ii < 8; ++ii)
        Qs[64 + grp * 8 + ii][c_loc] = pr[ii];
    __syncthreads();

    // ---- Et: Ps rows 64..127
    float sr = sig[r0 + lr];
#pragma unroll
    for (int ii = 0; ii < 8; ++ii) {
        int j = kb * 8 + ii;              // 0..63
        float e = sr * V[(63 - j) * INSIZE + r0 + lr];
#pragma unroll 8
        for (int i = 0; i < 64; ++i)
            e -= Ps[i][lr] * Xs[i * 64 + j];
        Ps[64 + j][lr] = e;
    }
    __syncthreads();

    // ---- 32x32x128 tile GEMM, 2x2 per thread; write Wt bf16 (transposed)
    int ty = t >> 4, tx = t & 15;
    float a00 = 0.f, a01 = 0.f, a10 = 0.f, a11 = 0.f;
#pragma unroll
    for (int k = 0; k < 128; ++k) {
        float2 a = *(const float2*)&Ps[k][ty * 2];
        float2 bq = *(const float2*)&Qs[k][tx * 2];
        a00 += a.x * bq.x; a01 += a.x * bq.y;
        a10 += a.y * bq.x; a11 += a.y * bq.y;
    }
    int rg = r0 + ty * 2, cg = c0 + tx * 2;
    float w00 = ((rg == cg) ? sig[rg] : 0.f) - a00;
    float w01 = ((rg == cg + 1) ? sig[rg] : 0.f) - a01;
    float w10 = ((rg + 1 == cg) ? sig[rg + 1] : 0.f) - a10;
    float w11 = ((rg + 1 == cg + 1) ? sig[rg + 1] : 0.f) - a11;
    unsigned short* Wt = (unsigned short*)(ws + OFF_WT);
    __hip_bfloat162 lo = __float22bfloat162_rn(make_float2(w00, w10));
    __hip_bfloat162 hi = __float22bfloat162_rn(make_float2(w01, w11));
    *(__hip_bfloat162*)&Wt[cg * INSIZE + rg] = lo;
    *(__hip_bfloat162*)&Wt[(cg + 1) * INSIZE + rg] = hi;
}

// ---------------------------------------------------------------------------
// out = x @ W + bias : bf16 MFMA, 64x64 block tile, BK=64, 1024 blocks
// (4 blocks/CU). Validated R10; epilogue now nontemporal (out is write-once,
// keep it out of L2 so X panels stay hot for the 8-blocks-per-panel reuse).
//   A: m=lane&15, k=(lane>>4)*8+j ; B: n=lane&15, k=(lane>>4)*8+j
//   C/D: col=lane&15, row=(lane>>4)*4+reg
typedef __attribute__((ext_vector_type(8))) short short8;
typedef __attribute__((ext_vector_type(4))) float float4v;

__global__ __launch_bounds__(256) void k_gemm(const float* __restrict__ X,
                                              const float* __restrict__ ws,
                                              const float* __restrict__ bias,
                                              float* __restrict__ out) {
    __shared__ float As[64 * 64];               // 16 KB, chunk-swizzled (16/row)
    __shared__ unsigned short Bs[64 * 64];      // 8 KB, chunk-swizzled (8/row)
    const unsigned short* Wt = (const unsigned short*)(ws + OFF_WT);

    // blocks sharing an X row-panel (same bm) share L%8 -> same XCD L2.
    int L = blockIdx.x;              // 0..1023
    int inner = L & 7;
    int bn = (L >> 3) & 7;           // 0..7
    int bm = (L >> 6) * 8 + inner;   // 0..127
    int row0 = bm * 64, col0 = bn * 64;

    int t = threadIdx.x;
    int l = t & 63, w = t >> 6;
    int wm = (w & 1) * 32, wn = (w >> 1) * 32;

    float4v acc[2][2] = {};
    int quad = l >> 4;
    int lan = l & 15;

    for (int k0 = 0; k0 < INSIZE; k0 += 64) {
        __syncthreads();
        // A: 64 rows x 64 k fp32 = 1024 16B-chunks; prow=P>>4, lc=(P&15)^(prow&15)
#pragma unroll
        for (int i = 0; i < 4; ++i) {
            int P = i * 256 + t;
            int prow = P >> 4, pc = P & 15;
            int lc = pc ^ (prow & 15);
            const float* g = X + (size_t)(row0 + prow) * INSIZE + k0 + lc * 4;
            __builtin_amdgcn_global_load_lds(
                (const __attribute__((address_space(1))) void*)g,
                (__attribute__((address_space(3))) void*)(As + P * 4), 16, 0, 0);
        }
        // B: 64 rows x 64 k bf16 = 512 16B-chunks; prow=P>>3, lc=(P&7)^(prow&7)
#pragma unroll
        for (int i = 0; i < 2; ++i) {
            int P = i * 256 + t;
            int prow = P >> 3, pc = P & 7;
            int lc = pc ^ (prow & 7);
            const unsigned short* g = Wt + (size_t)(col0 + prow) * INSIZE + k0 + lc * 8;
            __builtin_amdgcn_global_load_lds(
                (const __attribute__((address_space(1))) void*)g,
                (__attribute__((address_space(3))) void*)(Bs + P * 8), 16, 0, 0);
        }
        __syncthreads();

#pragma unroll
        for (int ki = 0; ki < 2; ++ki) {
            short8 af[2];
            short8 bf[2];
#pragma unroll
            for (int mi = 0; mi < 2; ++mi) {
                int rl = wm + mi * 16 + lan;
                int c0q = ki * 8 + quad * 2;
                const float4v lo = *(const float4v*)(As + (rl * 16 + (c0q ^ (rl & 15))) * 4);
                const float4v hi = *(const float4v*)(As + (rl * 16 + ((c0q + 1) ^ (rl & 15))) * 4);
                union { short8 s; __hip_bfloat162 h[4]; } u;
                u.h[0] = __float22bfloat162_rn(make_float2(lo[0], lo[1]));
                u.h[1] = __float22bfloat162_rn(make_float2(lo[2], lo[3]));
                u.h[2] = __float22bfloat162_rn(make_float2(hi[0], hi[1]));
                u.h[3] = __float22bfloat162_rn(make_float2(hi[2], hi[3]));
                af[mi] = u.s;
            }
#pragma unroll
            for (int ni = 0; ni < 2; ++ni) {
                int rn = wn + ni * 16 + lan;
                int c = (ki * 4 + quad) ^ (rn & 7);
                bf[ni] = *(const short8*)(Bs + (rn * 8 + c) * 8);
            }
#pragma unroll
            for (int mi = 0; mi < 2; ++mi)
#pragma unroll
                for (int ni = 0; ni < 2; ++ni)
                    acc[mi][ni] = __builtin_amdgcn_mfma_f32_16x16x32_bf16(
                        af[mi], bf[ni], acc[mi][ni], 0, 0, 0);
        }
    }

#pragma unroll
    for (int ni = 0; ni < 2; ++ni) {
        int c = col0 + wn + ni * 16 + lan;
        float bv = bias[c];
#pragma unroll
        for (int mi = 0; mi < 2; ++mi) {
            int rbase = row0 + wm + mi * 16 + quad * 4;
#pragma unroll
            for (int r = 0; r < 4; ++r)
                __builtin_nontemporal_store(acc[mi][ni][r] + bv,
                    &out[(size_t)(rbase + r) * INSIZE + c]);
        }
    }
}

// ---------------------------------------------------------------------------
extern "C" void kernel_launch(void* const* d_in, const int* in_sizes, int n_in,
                              void* d_out, int out_size, void* d_ws, size_t ws_size,
                              hipStream_t stream) {
    const float* x    = (const float*)d_in[0];
    const float* p    = (const float*)d_in[1];
    const float* U    = (const float*)d_in[2];
    const float* V    = (const float*)d_in[3];
    const float* bias = (const float*)d_in[4];
    float* ws  = (float*)d_ws;
    float* out = (float*)d_out;

    k_prep<<<193, 256, 0, stream>>>(U, V, p, ws);
    k_WtE<<<256, 256, 0, stream>>>(U, V, ws);
    k_gemm<<<1024, 256, 0, stream>>>(x, ws, bias, out);
}

// Round 12
// 110.875 us; speedup vs baseline: 1.0207x; 1.0207x over previous
//
#include <hip/hip_runtime.h>
#include <hip/hip_bf16.h>
#include <math.h>

// SpectralLinear: out = x @ (M_U * diag(sigma) * M_V) + bias
// Compact WY without explicit T:  T^{-1} = strict_upper(G) + diag(1/beta)
//   A = Umat*T_U (forward subst)   R = T_V*Vmat^T (backward subst)
//   C = (Umat^T S) Vmat ;  E = SV - A*C ;  W = S - [A | E] . [SU^T ; R]
// Inputs U,V are already upper-triangular (setup applies jnp.triu).
// R5: no device-scope spin barriers. R7: no serial prologue in wide kernels.
// R9: 8-lane parallel recurrences fused into k_WtE (3 launches).
// R10: register-resident k_prep; BK=64 gemm.  == BEST (111.5 us) ==
// R11 lessons (both reverted): triangle-skip doesn't cut the critical-path
// block; nontemporal epilogue stores defeat L2 write-combining.

#define INSIZE 512
#define NREF 64
#define BATCH 8192

// workspace layout (float slots)
static constexpr int OFF_WT    = 0;                    // 512*512 bf16 = 131072 slots
static constexpr int OFF_SIGMA = 131072;               // 512
static constexpr int OFF_BETAU = OFF_SIGMA + 512;      // 64
static constexpr int OFF_BETAV = OFF_BETAU + 64;       // 64
static constexpr int OFF_GU    = OFF_BETAV + 64;       // 64*64 strict-UPPER masked
static constexpr int OFF_GV    = OFF_GU + 4096;        // 64*64 strict-LOWER masked
static constexpr int OFF_C     = OFF_GV + 4096;        // 64*64

__device__ inline float sigma_of(float pv) {
    float s = 1.0f / (1.0f + expf(-pv));
    return 0.55f + 0.9f * (s - 0.5f);   // SIGMA_MIN=0.1, SIGMA_MAX=1.0
}

__device__ inline float dot8(float4 a0, float4 a1, float4 b0, float4 b1) {
    return a0.x * b0.x + a0.y * b0.y + a0.z * b0.z + a0.w * b0.w
         + a1.x * b1.x + a1.y * b1.y + a1.z * b1.z + a1.w * b1.w;
}

// ---------------------------------------------------------------------------
// k_prep: blocks 0..63   -> G_U row i masked j>i (+beta_U[i])
//         blocks 64..127 -> G_V row i masked j<i (+beta_V[i]) (packed: row 63-i)
//         blocks 128..191-> C row i
//         block 192      -> sigma
// Register-resident: lane l holds its 8 row-i elements (2 float4s) and dots
// against coalesced float4 loads of row j. No LDS, no __syncthreads.
__global__ __launch_bounds__(256) void k_prep(const float* __restrict__ U,
                                              const float* __restrict__ V,
                                              const float* __restrict__ p,
                                              float* __restrict__ ws) {
    int b = blockIdx.x, t = threadIdx.x;
    if (b == 192) {
        for (int c = t; c < INSIZE; c += 256)
            (ws + OFF_SIGMA)[c] = sigma_of(p[c]);
        return;
    }
    int w = t >> 6, l = t & 63;
    float4 b0, b1;
    if (b < 128) {
        bool isV = (b >= 64);
        int i = isV ? (b - 64) : b;
        const float* src = isV ? V : U;
        int srow = isV ? (63 - i) : i;
        const float4* ri4 = (const float4*)(src + srow * INSIZE);
        b0 = ri4[l * 2]; b1 = ri4[l * 2 + 1];
        float* G = ws + (isV ? OFF_GV : OFF_GU);
        float* beta = ws + (isV ? OFF_BETAV : OFF_BETAU);
        for (int jj = 0; jj < 16; ++jj) {
            int j = w * 16 + jj;
            int jrow = isV ? (63 - j) : j;
            const float4* rj4 = (const float4*)(src + jrow * INSIZE);
            float s = dot8(rj4[l * 2], rj4[l * 2 + 1], b0, b1);
            for (int o = 32; o > 0; o >>= 1) s += __shfl_down(s, o, 64);
            if (l == 0) {
                bool keep = isV ? (j < i) : (j > i);   // pre-masked triangles
                G[i * 64 + j] = keep ? s : 0.0f;
                if (j == i) beta[i] = 2.0f / s;
            }
        }
    } else {
        int i = b - 128;
        const float4* ui4 = (const float4*)(U + i * INSIZE);
        const float4* p4 = (const float4*)p;
        float4 u0 = ui4[l * 2], u1 = ui4[l * 2 + 1];
        float4 p0 = p4[l * 2], p1 = p4[l * 2 + 1];
        b0.x = u0.x * sigma_of(p0.x); b0.y = u0.y * sigma_of(p0.y);
        b0.z = u0.z * sigma_of(p0.z); b0.w = u0.w * sigma_of(p0.w);
        b1.x = u1.x * sigma_of(p1.x); b1.y = u1.y * sigma_of(p1.y);
        b1.z = u1.z * sigma_of(p1.z); b1.w = u1.w * sigma_of(p1.w);
        float* C = ws + OFF_C;
        for (int jj = 0; jj < 16; ++jj) {
            int j = w * 16 + jj;
            const float4* rj4 = (const float4*)(V + (63 - j) * INSIZE);
            float s = dot8(rj4[l * 2], rj4[l * 2 + 1], b0, b1);
            for (int o = 32; o > 0; o >>= 1) s += __shfl_down(s, o, 64);
            if (l == 0) C[i * 64 + j] = s;
        }
    }
}

// ---------------------------------------------------------------------------
// Fused: parallel substitutions + E + W tile + transpose + bf16 cast.
// Validated R9/R10; unchanged.
__global__ __launch_bounds__(256) void k_WtE(const float* __restrict__ U,
                                             const float* __restrict__ V,
                                             float* __restrict__ ws) {
    __shared__ float Ps[128][34];
    __shared__ float Qs[128][34];
    __shared__ float Xs[4160];
    int t = threadIdx.x;
    int r0 = (blockIdx.x >> 4) * 32;
    int c0 = (blockIdx.x & 15) * 32;
    const float* sig = ws + OFF_SIGMA;
    float* Qf = &Qs[0][0];

    // ---- phase a: stage masked Gram matrices + betas
    for (int i = t; i < 1024; i += 256) {
        *(float4*)&Xs[i * 4] = *(const float4*)&(ws + OFF_GU)[i * 4];
        *(float4*)&Qf[i * 4] = *(const float4*)&(ws + OFF_GV)[i * 4];
    }
    if (t < 64) {
        Xs[4096 + t] = (ws + OFF_BETAU)[t];
        Qf[4096 + t] = (ws + OFF_BETAV)[t];
    }
    __syncthreads();

    // ---- phase b: 8-lane-per-column parallel recurrences
    int l = t & 63;
    int c_loc = (t >> 6) * 8 + (l >> 3);   // 0..31
    int grp = l & 7;
    int srcbase = l & 0x38;
    float pj[8], pr[8];
    {   // forward: At columns r0..r0+31
        int r = r0 + c_loc;
#pragma unroll
        for (int jj = 0; jj < 8; ++jj) pj[jj] = U[(grp * 8 + jj) * INSIZE + r];
#pragma unroll
        for (int m = 0; m < 64; ++m) {
            float tmp = pj[m & 7] * Xs[4096 + m];
            float am = __shfl(tmp, srcbase | (m >> 3), 64);
            if (grp == (m >> 3)) pj[m & 7] = am;
#pragma unroll
            for (int jj = 0; jj < 8; ++jj)
                pj[jj] -= am * Xs[m * 64 + grp * 8 + jj];   // masked: j<=m is 0
        }
#pragma unroll
        for (int jj = 0; jj < 8; ++jj) Ps[grp * 8 + jj][c_loc] = pj[jj];
    }
    {   // backward: R columns c0..c0+31 (G_V symmetric, strict-lower masked)
        int c = c0 + c_loc;
#pragma unroll
        for (int ii = 0; ii < 8; ++ii)
            pr[ii] = V[(63 - (grp * 8 + ii)) * INSIZE + c];
#pragma unroll
        for (int i = 63; i >= 0; --i) {
            float tmp = pr[i & 7] * Qf[4096 + i];
            float ai = __shfl(tmp, srcbase | (i >> 3), 64);
            if (grp == (i >> 3)) pr[i & 7] = ai;
#pragma unroll
            for (int ii = 0; ii < 8; ++ii)
                pr[ii] -= ai * Qf[i * 64 + grp * 8 + ii];   // masked: j>=i is 0
        }
    }
    __syncthreads();   // G_U/G_V dead; Ps rows 0..63 = At tile

    // ---- phase c: C -> Xs; Qs rows 0..63 = SU^T, rows 64..127 = R (regs)
    for (int i = t; i < 1024; i += 256)
        *(float4*)&Xs[i * 4] = *(const float4*)&(ws + OFF_C)[i * 4];
    int lr = t & 31, kb = t >> 5;         // kb 0..7
    float sc = sig[c0 + lr];
#pragma unroll
    for (int ii = 0; ii < 8; ++ii) {
        int k = kb + ii * 8;              // 0..63
        Qs[k][lr] = U[k * INSIZE + c0 + lr] * sc;
    }
#pragma unroll
    for (int ii = 0; ii < 8; ++ii)
        Qs[64 + grp * 8 + ii][c_loc] = pr[ii];
    __syncthreads();

    // ---- Et: Ps rows 64..127
    float sr = sig[r0 + lr];
#pragma unroll
    for (int ii = 0; ii < 8; ++ii) {
        int j = kb * 8 + ii;              // 0..63
        float e = sr * V[(63 - j) * INSIZE + r0 + lr];
#pragma unroll 8
        for (int i = 0; i < 64; ++i)
            e -= Ps[i][lr] * Xs[i * 64 + j];
        Ps[64 + j][lr] = e;
    }
    __syncthreads();

    // ---- 32x32x128 tile GEMM, 2x2 per thread; write Wt bf16 (transposed)
    int ty = t >> 4, tx = t & 15;
    float a00 = 0.f, a01 = 0.f, a10 = 0.f, a11 = 0.f;
#pragma unroll
    for (int k = 0; k < 128; ++k) {
        float2 a = *(const float2*)&Ps[k][ty * 2];
        float2 bq = *(const float2*)&Qs[k][tx * 2];
        a00 += a.x * bq.x; a01 += a.x * bq.y;
        a10 += a.y * bq.x; a11 += a.y * bq.y;
    }
    int rg = r0 + ty * 2, cg = c0 + tx * 2;
    float w00 = ((rg == cg) ? sig[rg] : 0.f) - a00;
    float w01 = ((rg == cg + 1) ? sig[rg] : 0.f) - a01;
    float w10 = ((rg + 1 == cg) ? sig[rg + 1] : 0.f) - a10;
    float w11 = ((rg + 1 == cg + 1) ? sig[rg + 1] : 0.f) - a11;
    unsigned short* Wt = (unsigned short*)(ws + OFF_WT);
    __hip_bfloat162 lo = __float22bfloat162_rn(make_float2(w00, w10));
    __hip_bfloat162 hi = __float22bfloat162_rn(make_float2(w01, w11));
    *(__hip_bfloat162*)&Wt[cg * INSIZE + rg] = lo;
    *(__hip_bfloat162*)&Wt[(cg + 1) * INSIZE + rg] = hi;
}

// ---------------------------------------------------------------------------
// out = x @ W + bias : bf16 MFMA, 64x64 block tile, BK=64, 1024 blocks
// (4 blocks/CU, 24 KB LDS). Validated R10; plain stores (NT regressed, R11).
//   A: m=lane&15, k=(lane>>4)*8+j ; B: n=lane&15, k=(lane>>4)*8+j
//   C/D: col=lane&15, row=(lane>>4)*4+reg
typedef __attribute__((ext_vector_type(8))) short short8;
typedef __attribute__((ext_vector_type(4))) float float4v;

__global__ __launch_bounds__(256) void k_gemm(const float* __restrict__ X,
                                              const float* __restrict__ ws,
                                              const float* __restrict__ bias,
                                              float* __restrict__ out) {
    __shared__ float As[64 * 64];               // 16 KB, chunk-swizzled (16/row)
    __shared__ unsigned short Bs[64 * 64];      // 8 KB, chunk-swizzled (8/row)
    const unsigned short* Wt = (const unsigned short*)(ws + OFF_WT);

    // blocks sharing an X row-panel (same bm) share L%8 -> same XCD L2.
    int L = blockIdx.x;              // 0..1023
    int inner = L & 7;
    int bn = (L >> 3) & 7;           // 0..7
    int bm = (L >> 6) * 8 + inner;   // 0..127
    int row0 = bm * 64, col0 = bn * 64;

    int t = threadIdx.x;
    int l = t & 63, w = t >> 6;
    int wm = (w & 1) * 32, wn = (w >> 1) * 32;

    float4v acc[2][2] = {};
    int quad = l >> 4;
    int lan = l & 15;

    for (int k0 = 0; k0 < INSIZE; k0 += 64) {
        __syncthreads();
        // A: 64 rows x 64 k fp32 = 1024 16B-chunks; prow=P>>4, lc=(P&15)^(prow&15)
#pragma unroll
        for (int i = 0; i < 4; ++i) {
            int P = i * 256 + t;
            int prow = P >> 4, pc = P & 15;
            int lc = pc ^ (prow & 15);
            const float* g = X + (size_t)(row0 + prow) * INSIZE + k0 + lc * 4;
            __builtin_amdgcn_global_load_lds(
                (const __attribute__((address_space(1))) void*)g,
                (__attribute__((address_space(3))) void*)(As + P * 4), 16, 0, 0);
        }
        // B: 64 rows x 64 k bf16 = 512 16B-chunks; prow=P>>3, lc=(P&7)^(prow&7)
#pragma unroll
        for (int i = 0; i < 2; ++i) {
            int P = i * 256 + t;
            int prow = P >> 3, pc = P & 7;
            int lc = pc ^ (prow & 7);
            const unsigned short* g = Wt + (size_t)(col0 + prow) * INSIZE + k0 + lc * 8;
            __builtin_amdgcn_global_load_lds(
                (const __attribute__((address_space(1))) void*)g,
                (__attribute__((address_space(3))) void*)(Bs + P * 8), 16, 0, 0);
        }
        __syncthreads();

#pragma unroll
        for (int ki = 0; ki < 2; ++ki) {
            short8 af[2];
            short8 bf[2];
#pragma unroll
            for (int mi = 0; mi < 2; ++mi) {
                int rl = wm + mi * 16 + lan;
                int c0q = ki * 8 + quad * 2;
                const float4v lo = *(const float4v*)(As + (rl * 16 + (c0q ^ (rl & 15))) * 4);
                const float4v hi = *(const float4v*)(As + (rl * 16 + ((c0q + 1) ^ (rl & 15))) * 4);
                union { short8 s; __hip_bfloat162 h[4]; } u;
                u.h[0] = __float22bfloat162_rn(make_float2(lo[0], lo[1]));
                u.h[1] = __float22bfloat162_rn(make_float2(lo[2], lo[3]));
                u.h[2] = __float22bfloat162_rn(make_float2(hi[0], hi[1]));
                u.h[3] = __float22bfloat162_rn(make_float2(hi[2], hi[3]));
                af[mi] = u.s;
            }
#pragma unroll
            for (int ni = 0; ni < 2; ++ni) {
                int rn = wn + ni * 16 + lan;
                int c = (ki * 4 + quad) ^ (rn & 7);
                bf[ni] = *(const short8*)(Bs + (rn * 8 + c) * 8);
            }
#pragma unroll
            for (int mi = 0; mi < 2; ++mi)
#pragma unroll
                for (int ni = 0; ni < 2; ++ni)
                    acc[mi][ni] = __builtin_amdgcn_mfma_f32_16x16x32_bf16(
                        af[mi], bf[ni], acc[mi][ni], 0, 0, 0);
        }
    }

#pragma unroll
    for (int ni = 0; ni < 2; ++ni) {
        int c = col0 + wn + ni * 16 + lan;
        float bv = bias[c];
#pragma unroll
        for (int mi = 0; mi < 2; ++mi) {
            int rbase = row0 + wm + mi * 16 + quad * 4;
#pragma unroll
            for (int r = 0; r < 4; ++r)
                out[(size_t)(rbase + r) * INSIZE + c] = acc[mi][ni][r] + bv;
        }
    }
}

// ---------------------------------------------------------------------------
extern "C" void kernel_launch(void* const* d_in, const int* in_sizes, int n_in,
                              void* d_out, int out_size, void* d_ws, size_t ws_size,
                              hipStream_t stream) {
    const float* x    = (const float*)d_in[0];
    const float* p    = (const float*)d_in[1];
    const float* U    = (const float*)d_in[2];
    const float* V    = (const float*)d_in[3];
    const float* bias = (const float*)d_in[4];
    float* ws  = (float*)d_ws;
    float* out = (float*)d_out;

    k_prep<<<193, 256, 0, stream>>>(U, V, p, ws);
    k_WtE<<<256, 256, 0, stream>>>(U, V, ws);
    k_gemm<<<1024, 256, 0, stream>>>(x, ws, bias, out);
}